// Round 1
// baseline (142.839 us; speedup 1.0000x reference)
//
#include <hip/hip_runtime.h>

// Dota2Eq3Embed: 2048 samples x 2 sides. Per (n,side):
//   v[i][d] = relu(embed[x[n,side,i]][d]), i<5, d<64
//   Equivariant layer over the rank-1 cube v_i v_j v_k reduces to per-channel
//   tables built from {v, S, S^2, S^3}; mean-pool commutes with wout.
// Output: (2048, 2) f32.

#define DEV __device__ __forceinline__

DEV constexpr int pid2(int a, int b) {
  int x = a < b ? a : b;
  int y = a < b ? b : a;
  return x * (9 - x) / 2 + y;            // 15 symmetric pairs, lexicographic
}
DEV constexpr int tid3(int i, int j, int k) {
  int a = i, b = j, c = k, t;
  if (a > b) { t = a; a = b; b = t; }
  if (b > c) { t = b; b = c; c = t; }
  if (a > b) { t = a; a = b; b = t; }
  // 35 symmetric triples, lexicographic (a<=b<=c)
  return a * (a * a - 18 * a + 107) / 6 + (b - a) * (11 - a - b) / 2 + (c - b);
}

__global__ __launch_bounds__(256, 2)
void dota2_eq3_kernel(const int* __restrict__ x,
                      const float* __restrict__ embed,
                      const float* __restrict__ coefs1, const float* __restrict__ bias1,
                      const float* __restrict__ wout1,  const float* __restrict__ bout1,
                      const float* __restrict__ coefs2, const float* __restrict__ bias2,
                      const float* __restrict__ wout2,  const float* __restrict__ bout2,
                      const float* __restrict__ fcw,    const float* __restrict__ fcb,
                      float* __restrict__ out)
{
  __shared__ float Feat[2][64][56];   // per-side, per-d: 35 triples | 15 S*pairs | 5 S2*v | S3
  __shared__ float hbarL[2][128];
  __shared__ float zL[256];

  const int n    = blockIdx.x;
  const int tid  = threadIdx.x;
  const int side = tid >> 7;          // waves 0,1 -> side 0; waves 2,3 -> side 1
  const int t2   = tid & 127;

  // ---------- Phase A: build per-d feature tables (threads t2<64, d=t2) ----------
  if (t2 < 64) {
    const int d = t2;
    const int* xn = x + n * 10 + side * 5;
    float v[5];
    #pragma unroll
    for (int i = 0; i < 5; ++i) v[i] = fmaxf(embed[xn[i] * 64 + d], 0.f);
    const float S  = v[0] + v[1] + v[2] + v[3] + v[4];
    const float S2 = S * S;
    const float S3 = S2 * S;
    float p2[15];
    {
      int c2 = 0;
      #pragma unroll
      for (int a = 0; a < 5; ++a)
        #pragma unroll
        for (int b = a; b < 5; ++b) { p2[c2] = v[a] * v[b]; ++c2; }
    }
    float* Fd = &Feat[side][d][0];
    {
      int c3 = 0;
      #pragma unroll
      for (int a = 0; a < 5; ++a)
        #pragma unroll
        for (int b = a; b < 5; ++b)
          #pragma unroll
          for (int c = b; c < 5; ++c) { Fd[c3] = p2[pid2(a, b)] * v[c]; ++c3; }
    }
    #pragma unroll
    for (int t = 0; t < 15; ++t) Fd[35 + t] = S * p2[t];
    #pragma unroll
    for (int i = 0; i < 5; ++i)  Fd[50 + i] = S2 * v[i];
    Fd[55] = S3;
  }
  __syncthreads();

  // ---------- Phase B: contraction over d (thread = channel s) ----------
  const int s = t2;
  const float* Cb = side ? coefs2 : coefs1;
  const float* bi = side ? bias2  : bias1;

  float g0[35], b1a[15], b2a[15], b3a[15], m4[5], m5[5], m6[5];
  float a7 = 0.f;
  #pragma unroll
  for (int t = 0; t < 35; ++t) g0[t] = 0.f;
  #pragma unroll
  for (int t = 0; t < 15; ++t) { b1a[t] = 0.f; b2a[t] = 0.f; b3a[t] = 0.f; }
  #pragma unroll
  for (int t = 0; t < 5; ++t)  { m4[t] = 0.f; m5[t] = 0.f; m6[t] = 0.f; }

  const float* Cs = Cb + s * 8;       // coefs[d][s][b], b contiguous
  for (int d = 0; d < 64; ++d) {
    const float4 cA = *reinterpret_cast<const float4*>(Cs + (size_t)d * 1024);
    const float4 cB = *reinterpret_cast<const float4*>(Cs + (size_t)d * 1024 + 4);
    const float* Fd = &Feat[side][d][0];
    #pragma unroll
    for (int t = 0; t < 35; ++t) g0[t] = fmaf(cA.x, Fd[t], g0[t]);
    #pragma unroll
    for (int t = 0; t < 15; ++t) {
      const float w = Fd[35 + t];
      b1a[t] = fmaf(cA.y, w, b1a[t]);
      b2a[t] = fmaf(cA.z, w, b2a[t]);
      b3a[t] = fmaf(cA.w, w, b3a[t]);
    }
    #pragma unroll
    for (int t = 0; t < 5; ++t) {
      const float u = Fd[50 + t];
      m4[t] = fmaf(cB.x, u, m4[t]);
      m5[t] = fmaf(cB.y, u, m5[t]);
      m6[t] = fmaf(cB.z, u, m6[t]);
    }
    a7 = fmaf(cB.w, Fd[55], a7);
  }

  // ---------- Assembly: sum of relu over 125 positions (all indices constexpr) ----------
  float hsum = 0.f;
  const float base = a7 + bi[s];
  #pragma unroll
  for (int i = 0; i < 5; ++i) {
    const float pi = base + m6[i];
    #pragma unroll
    for (int j = 0; j < 5; ++j) {
      const float pij = pi + m5[j] + b3a[pid2(i, j)];
      #pragma unroll
      for (int k = 0; k < 5; ++k) {
        const float val = pij + m4[k] + b2a[pid2(i, k)] + b1a[pid2(j, k)] + g0[tid3(i, j, k)];
        hsum += fmaxf(val, 0.f);
      }
    }
  }
  hbarL[side][s] = hsum * (1.f / 125.f);
  __syncthreads();

  // ---------- Phase C: te[o] = relu(hbar @ wout + bout), per side ----------
  {
    const int o = t2;
    const float* W  = side ? wout2 : wout1;
    const float* bo = side ? bout2 : bout1;
    float acc = bo[o];
    #pragma unroll 4
    for (int ss = 0; ss < 128; ++ss) acc = fmaf(hbarL[side][ss], W[ss * 128 + o], acc);
    zL[side * 128 + o] = fmaxf(acc, 0.f);
  }
  __syncthreads();

  // ---------- Phase D: final FC (256 -> 2) ----------
  if (tid < 2) {
    const int c = tid;
    float acc = fcb[c];
    #pragma unroll 8
    for (int q = 0; q < 256; ++q) acc = fmaf(zL[q], fcw[q * 2 + c], acc);
    out[n * 2 + c] = acc;
  }
}

extern "C" void kernel_launch(void* const* d_in, const int* in_sizes, int n_in,
                              void* d_out, int out_size, void* d_ws, size_t ws_size,
                              hipStream_t stream) {
  const int*   x      = (const int*)  d_in[0];
  const float* embed  = (const float*)d_in[1];
  const float* coefs1 = (const float*)d_in[2];
  const float* bias1  = (const float*)d_in[3];
  const float* wout1  = (const float*)d_in[4];
  const float* bout1  = (const float*)d_in[5];
  const float* coefs2 = (const float*)d_in[6];
  const float* bias2  = (const float*)d_in[7];
  const float* wout2  = (const float*)d_in[8];
  const float* bout2  = (const float*)d_in[9];
  const float* fcw    = (const float*)d_in[10];
  const float* fcb    = (const float*)d_in[11];
  float* out = (float*)d_out;

  const int batch = in_sizes[0] / 10;   // x: (B, 2, 5)
  dota2_eq3_kernel<<<batch, 256, 0, stream>>>(
      x, embed, coefs1, bias1, wout1, bout1,
      coefs2, bias2, wout2, bout2, fcw, fcb, out);
}